// Round 3
// baseline (2626.039 us; speedup 1.0000x reference)
//
#include <hip/hip_runtime.h>
#include <hip/hip_bf16.h>

#define TT   2048
#define BB   512
#define IN_  27
#define HH   64
#define NG   256   // 4*H
#define OUTD 26
#define EPSV 1e-5f

__device__ __forceinline__ float sigm(float x) {
    return 1.0f / (1.0f + __expf(-x));
}

__device__ __forceinline__ float tanh_fast(float x) {
    float e = __expf(-2.0f * fabsf(x));
    float r = (1.0f - e) / (1.0f + e);
    return copysignf(r, x);
}

// 27-element repetition macro (x inputs / W_ih weights as NAMED variables so
// the compiler keeps them in registers — arrays were demoted to scratch in R1:
// VGPR_Count=56 proved wi[]/wh[] never lived in VGPRs).
#define FOR27(F) F(0)F(1)F(2)F(3)F(4)F(5)F(6)F(7)F(8)F(9)F(10)F(11)F(12) \
                 F(13)F(14)F(15)F(16)F(17)F(18)F(19)F(20)F(21)F(22)F(23)F(24)F(25)F(26)

// readlane broadcast of h[k] (k compile-time constant)
#define RLH(k) __int_as_float(__builtin_amdgcn_readlane(__float_as_int(hv), (k)))

// Phase 1: sequential LSTM. One block (256 thr) per batch element.
// thread = gate j; lane l of every wave holds h[l], c[l] replicated.
__global__ __launch_bounds__(256, 2) void lstm_seq(
    const float* __restrict__ x,     // [T,B,IN]
    const float* __restrict__ W_ih,  // [NG,IN]
    const float* __restrict__ W_hh,  // [NG,H]
    const float* __restrict__ b_ih,  // [NG]
    const float* __restrict__ b_hh,  // [NG]
    float* __restrict__ h_all,       // [tc,B,H]
    float* __restrict__ state,       // [2,B,H]
    int t0, int tc, int first)
{
    const int b = blockIdx.x;
    const int j = threadIdx.x;
    const int q = j >> 6;        // 0=i 1=f 2=g 3=o (wave-uniform)
    const int l = j & 63;

    // --- W_hh row j: 16 named float4 (row is 256 B, 16B-aligned) ---
    const float4* whv = (const float4*)(W_hh) + (size_t)j * 16;
    float4 w00 = whv[0],  w01 = whv[1],  w02 = whv[2],  w03 = whv[3];
    float4 w04 = whv[4],  w05 = whv[5],  w06 = whv[6],  w07 = whv[7];
    float4 w08 = whv[8],  w09 = whv[9],  w10 = whv[10], w11 = whv[11];
    float4 w12 = whv[12], w13 = whv[13], w14 = whv[14], w15 = whv[15];

    // --- W_ih row j: 27 named floats (rows are 108 B, not vec-alignable) ---
    const float* wip = W_ih + (size_t)j * IN_;
#define DWI(i) float wi##i = wip[i];
    FOR27(DWI)
#undef DWI

    const float bias = b_ih[j] + b_hh[j];

    float hv, cv;
    if (first) { hv = 0.0f; cv = 0.0f; }
    else {
        hv = state[b * HH + l];
        cv = state[BB * HH + b * HH + l];
    }

    // x scalars: wave-uniform (address depends only on blockIdx/t) -> SGPRs.
    // Double set for distance-1 prefetch across the sequential step.
#define DXN(i) float xn##i;
    FOR27(DXN)
#undef DXN
#define DXC(i) float xc##i;
    FOR27(DXC)
#undef DXC
    {
        const float* xr = x + ((size_t)t0 * BB + b) * IN_;
#define LXN(i) xn##i = xr[i];
        FOR27(LXN)
#undef LXN
    }

    __shared__ float acts[2][NG];  // double-buffered -> one barrier per step

    for (int tl = 0; tl < tc; ++tl) {
        // rotate prefetched x into current, issue next step's uniform loads
#define CPX(i) xc##i = xn##i;
        FOR27(CPX)
#undef CPX
        {
            int tnext = t0 + tl + 1;
            if (tnext > TT - 1) tnext = TT - 1;   // clamp (value unused at tail)
            const float* xr = x + ((size_t)tnext * BB + b) * IN_;
#define LXN(i) xn##i = xr[i];
            FOR27(LXN)
#undef LXN
        }

        // gate_j = bias + W_hh[j,:].h + W_ih[j,:].x_t   (4 accumulators)
        float a0 = bias, a1 = 0.0f, a2 = 0.0f, a3 = 0.0f;
#define HDOT(m, V) \
        a0 = fmaf(RLH(4*(m)+0), (V).x, a0); \
        a1 = fmaf(RLH(4*(m)+1), (V).y, a1); \
        a2 = fmaf(RLH(4*(m)+2), (V).z, a2); \
        a3 = fmaf(RLH(4*(m)+3), (V).w, a3);
        HDOT(0, w00)  HDOT(1, w01)  HDOT(2, w02)  HDOT(3, w03)
        HDOT(4, w04)  HDOT(5, w05)  HDOT(6, w06)  HDOT(7, w07)
        HDOT(8, w08)  HDOT(9, w09)  HDOT(10, w10) HDOT(11, w11)
        HDOT(12, w12) HDOT(13, w13) HDOT(14, w14) HDOT(15, w15)
#undef HDOT

#define XF(i, a) a = fmaf(xc##i, wi##i, a);
        XF(0, a0)  XF(1, a1)  XF(2, a2)  XF(3, a3)
        XF(4, a0)  XF(5, a1)  XF(6, a2)  XF(7, a3)
        XF(8, a0)  XF(9, a1)  XF(10, a2) XF(11, a3)
        XF(12, a0) XF(13, a1) XF(14, a2) XF(15, a3)
        XF(16, a0) XF(17, a1) XF(18, a2) XF(19, a3)
        XF(20, a0) XF(21, a1) XF(22, a2) XF(23, a3)
        XF(24, a0) XF(25, a1) XF(26, a2)
#undef XF
        const float acc = (a0 + a1) + (a2 + a3);

        const float av = (q == 2) ? tanh_fast(acc) : sigm(acc);

        acts[tl & 1][j] = av;
        __syncthreads();

        const float gi = acts[tl & 1][l];
        const float gf = acts[tl & 1][HH + l];
        const float gg = acts[tl & 1][2 * HH + l];
        const float go = acts[tl & 1][3 * HH + l];

        const float cn = fmaf(gf, cv, gi * gg);
        const float hn = go * tanh_fast(cn);
        cv = cn;
        hv = hn;

        if (q == 0) h_all[((size_t)tl * BB + b) * HH + l] = hn;
        // no trailing barrier: next step writes the OTHER acts buffer, and
        // this buffer is only overwritten after the next barrier.
    }

    if (q == 0) {
        state[b * HH + l] = hv;
        state[BB * HH + b * HH + l] = cv;
    }
}

// Phase 2: per-timestep BatchNorm (batch stats) + locked dropout + maxpool
// over batch + FC. One block per timestep, fully parallel.
__global__ __launch_bounds__(256, 2) void bn_pool_fc(
    const float* __restrict__ h_all,  // [tc,B,H]
    const float* __restrict__ gamma,
    const float* __restrict__ beta,
    const float* __restrict__ dmask,  // [B,H]
    const float* __restrict__ pg,     // [T,OUT]
    const float* __restrict__ W_fc,   // [OUT, H+OUT]
    const float* __restrict__ b_fc,
    float* __restrict__ y,            // [T,OUT]
    int t0, int tc)
{
    const int tl = blockIdx.x;
    const int t = t0 + tl;
    const int tid = threadIdx.x;
    const int g = tid >> 6;
    const int hcol = tid & 63;
    const float* hp = h_all + (size_t)tl * BB * HH;

    __shared__ float s_a[4][HH];
    __shared__ float s_b[4][HH];
    __shared__ float s_scale[HH];
    __shared__ float s_shift[HH];
    __shared__ float s_pool[HH];

    float sum = 0.0f, sq = 0.0f;
    for (int bb = g; bb < BB; bb += 4) {
        const float v = hp[bb * HH + hcol];
        sum += v;
        sq = fmaf(v, v, sq);
    }
    s_a[g][hcol] = sum;
    s_b[g][hcol] = sq;
    __syncthreads();

    if (tid < HH) {
        const float s  = (s_a[0][tid] + s_a[1][tid]) + (s_a[2][tid] + s_a[3][tid]);
        const float q2 = (s_b[0][tid] + s_b[1][tid]) + (s_b[2][tid] + s_b[3][tid]);
        const float mean = s * (1.0f / BB);
        const float var  = q2 * (1.0f / BB) - mean * mean;
        const float rs = rsqrtf(var + EPSV);
        const float sc = rs * gamma[tid];
        s_scale[tid] = sc;
        s_shift[tid] = beta[tid] - mean * sc;
    }
    __syncthreads();

    const float sc = s_scale[hcol];
    const float sh = s_shift[hcol];
    float m = -3.0e38f;
    for (int bb = g; bb < BB; bb += 4) {
        const float v = hp[bb * HH + hcol];
        const float hd = fmaf(v, sc, sh) * dmask[bb * HH + hcol];
        m = fmaxf(m, hd);
    }
    s_a[g][hcol] = m;
    __syncthreads();
    if (tid < HH) {
        s_pool[tid] = fmaxf(fmaxf(s_a[0][tid], s_a[1][tid]),
                            fmaxf(s_a[2][tid], s_a[3][tid]));
    }
    __syncthreads();

    if (tid < OUTD) {
        float acc = b_fc[tid];
        const float* w = W_fc + tid * (HH + OUTD);
#pragma unroll
        for (int k = 0; k < HH; ++k) acc = fmaf(w[k], s_pool[k], acc);
#pragma unroll
        for (int k = 0; k < OUTD; ++k) acc = fmaf(w[HH + k], pg[t * OUTD + k], acc);
        y[t * OUTD + tid] = acc;
    }
}

extern "C" void kernel_launch(void* const* d_in, const int* in_sizes, int n_in,
                              void* d_out, int out_size, void* d_ws, size_t ws_size,
                              hipStream_t stream)
{
    const float* x     = (const float*)d_in[0];
    const float* pg    = (const float*)d_in[1];
    const float* W_ih  = (const float*)d_in[2];
    const float* W_hh  = (const float*)d_in[3];
    const float* b_ih  = (const float*)d_in[4];
    const float* b_hh  = (const float*)d_in[5];
    const float* gamma = (const float*)d_in[6];
    const float* beta  = (const float*)d_in[7];
    const float* W_fc  = (const float*)d_in[8];
    const float* b_fc  = (const float*)d_in[9];
    const float* dmask = (const float*)d_in[10];
    float* y = (float*)d_out;

    const size_t state_bytes = 2ull * BB * HH * sizeof(float);
    const size_t per_t = (size_t)BB * HH * sizeof(float);
    size_t avail = (ws_size > state_bytes) ? (ws_size - state_bytes) : 0;
    int chunkT = (int)(avail / per_t);
    if (chunkT > TT) chunkT = TT;
    if (chunkT < 1) chunkT = 1;

    float* h_all = (float*)d_ws;
    float* state = (float*)((char*)d_ws + (size_t)chunkT * per_t);

    int first = 1;
    for (int t0 = 0; t0 < TT; t0 += chunkT) {
        int tc = TT - t0;
        if (tc > chunkT) tc = chunkT;
        lstm_seq<<<BB, 256, 0, stream>>>(x, W_ih, W_hh, b_ih, b_hh,
                                         h_all, state, t0, tc, first);
        bn_pool_fc<<<tc, 256, 0, stream>>>(h_all, gamma, beta, dmask, pg,
                                           W_fc, b_fc, y, t0, tc);
        first = 0;
    }
}